// Round 8
// baseline (150.051 us; speedup 1.0000x reference)
//
#include <hip/hip_runtime.h>
#include <stdint.h>

// Problem constants
#define B_   16
#define D_   256
#define T_   4096
#define K_   1024
#define N_   (B_ * T_)      // 65536 points
#define SUBP 64             // points per sub-tile
#define NSUB 4              // sub-tiles per block (block = 256 points)

typedef __attribute__((ext_vector_type(4))) float floatx4;
typedef __attribute__((ext_vector_type(2))) float floatx2;
typedef __attribute__((ext_vector_type(2))) long longx2;

// ---- Kernel 0: emb fp32 -> fp8 e4m3 (scaled x1024), stored in PIECE order:
// tile ct = codes [ct*16, ct*16+16), 4 KB = 4 pieces of 1 KB. Byte for
// (code c, dim d): ct=c>>4, ml=c&15, kk=d>>5, quad=(d>>3)&3, b=d&7 at
//   ct*4096 + (kk>>1)*1024 + (quad*16+ml)*16 + (kk&1)*8 + b
// esqh[c] = 1024*0.5*||e_exact||^2. Also zeroes loss.
__global__ __launch_bounds__(256) void emb_prep(const float* __restrict__ emb,
                                                uint32_t* __restrict__ embf8,
                                                float* __restrict__ esqh,
                                                float* __restrict__ lossp) {
    int w = threadIdx.x >> 6, lane = threadIdx.x & 63;
    int k = blockIdx.x * 4 + w;                       // one wave per code row
    float4 v = ((const float4*)emb)[k * 64 + lane];   // d0 = lane*4
    float a0 = v.x * 1024.f, a1 = v.y * 1024.f, a2 = v.z * 1024.f, a3 = v.w * 1024.f;
    int p = __builtin_amdgcn_cvt_pk_fp8_f32(a0, a1, 0, false);
    p = __builtin_amdgcn_cvt_pk_fp8_f32(a2, a3, p, true);
    int kk = lane >> 3, quad = (lane >> 1) & 3;       // from d0 = lane*4
    int widx = (k >> 4) * 1024 + (kk >> 1) * 256 + (quad * 16 + (k & 15)) * 4
             + (kk & 1) * 2 + (lane & 1);
    embf8[widx] = (uint32_t)p;
    float ss = a0 * a0 + a1 * a1 + a2 * a2 + a3 * a3;   // exact (pre-fp8) scaled norm
    #pragma unroll
    for (int off = 32; off; off >>= 1) ss += __shfl_xor(ss, off, 64);
    if (lane == 0) esqh[k] = ss * (0.5f / 1024.f);      // = 1024 * 0.5*||e||^2
    if (blockIdx.x == 0 && threadIdx.x == 0) *lossp = 0.f;
}

// ---- Main kernel (R8: producer-consumer wave specialization) ----
// R0-R7 accounting: per-CU MFMA ~16.6us + VALU ~15us + mem ~16us SUM to the
// measured ~49us because all waves run the same phase in lockstep (every
// pipe 20-30% busy). R8 puts DIFFERENT pipe work on each CU concurrently:
// grid 256 (1 block/CU), 512 thr = 8 waves, persistent over NSUB=4
// sub-tiles of 64 pts:
//   waves 0-3: R3's verified k-loop (code quarter x all 64 pts, 32
//              MFMA/tile, qq dbuf, ~150 regs) on xs[i&1]
//   waves 4-5: P1 staging of sub-tile i+1 -> xs[(i+1)&1]
//   waves 6-7: P4 of sub-tile i-1, gather+dequant FUSED thread-locally
//              (no LDS staging; stores drain under the k-loop, not at a
//              barrier -> no vmcnt(0) drain stall)
// 2 barriers/iter; between them only the 64-lane merge. pidx/zred double-
// buffered by parity; ledger: P1 writes par^1 while compute reads par;
// P4(i-1) reads pidx[par^1] written by merge(i-1) two barriers earlier;
// zredp[par] written at iter i-1 pre-A, read at merge(i) post-A. 1 compute
// + 1 memory wave per SIMD -> MFMA/VALU/VMEM pipes co-run (m114).
// launch_bounds(512,2): combined reg cap 256 >> ~170 demand -> no spill.
// Compute path byte-identical to R3 -> absmax stays 0.001953125.
__global__ __launch_bounds__(512, 2) void vq_main(const float* __restrict__ z,
                                                  const uint32_t* __restrict__ embf8,
                                                  const float* __restrict__ esqh,
                                                  float* __restrict__ out0,
                                                  float* __restrict__ lossp) {
    __shared__ __align__(16) unsigned char xs[2][SUBP * 256];   // 32 KiB
    __shared__ float wvals[4][SUBP];
    __shared__ int   pidx[2][SUBP];
    __shared__ float zredp[2][2];
    __shared__ float zred0[8];

    int tid  = threadIdx.x;
    int lane = tid & 63, w = tid >> 6;        // 8 waves
    int ml   = lane & 15, quad = lane >> 4;
    int blk  = blockIdx.x;                    // 256 blocks = 16 per image
    int b    = blk >> 4;
    int t00  = (blk & 15) * (NSUB * SUBP);
    const float* zb = z + (size_t)b * (D_ * T_) + t00;
    float* ob = out0 + (size_t)b * (D_ * T_) + t00;

// P1 of sub-tile S: M = wave-slot, NW = number of participating waves.
// Covers dgrp = M + NW*j for j in [0, 32/NW); all 64 t's via lanes.
#define P1_BODY(S, M, NW, OUT)                                                  \
    {                                                                           \
        int t = lane, hf = (t >> 4) & 1;                                        \
        const float* zbS = zb + (S) * SUBP;                                     \
        unsigned char* xsd = xs[(S) & 1];                                       \
        float zsq = 0.f;                                                        \
        _Pragma("unroll 2")                                                     \
        for (int j = 0; j < 32 / (NW); ++j) {                                   \
            int dgrp = (M) + (NW) * j;                                          \
            int d0 = dgrp * 8;                                                  \
            float f0 = zbS[(d0 + 0) * T_ + t];                                  \
            float f1 = zbS[(d0 + 1) * T_ + t];                                  \
            float f2 = zbS[(d0 + 2) * T_ + t];                                  \
            float f3 = zbS[(d0 + 3) * T_ + t];                                  \
            float f4 = zbS[(d0 + 4) * T_ + t];                                  \
            float f5 = zbS[(d0 + 5) * T_ + t];                                  \
            float f6 = zbS[(d0 + 6) * T_ + t];                                  \
            float f7 = zbS[(d0 + 7) * T_ + t];                                  \
            zsq += f0*f0 + f1*f1 + f2*f2 + f3*f3 + f4*f4 + f5*f5 + f6*f6 + f7*f7; \
            uint32_t p0 = (uint32_t)__builtin_amdgcn_cvt_pk_fp8_f32(f0, f1, 0, false); \
            p0 = (uint32_t)__builtin_amdgcn_cvt_pk_fp8_f32(f2, f3, (int)p0, true); \
            uint32_t p1 = (uint32_t)__builtin_amdgcn_cvt_pk_fp8_f32(f4, f5, 0, false); \
            p1 = (uint32_t)__builtin_amdgcn_cvt_pk_fp8_f32(f6, f7, (int)p1, true); \
            int c = dgrp >> 1, h = dgrp & 1;                                    \
            *(uint2*)&xsd[t * 256 + ((c ^ (t & 15)) << 4) + ((h ^ hf) << 3)] =  \
                make_uint2(p0, p1);                                             \
        }                                                                       \
        _Pragma("unroll")                                                       \
        for (int off = 32; off; off >>= 1) zsq += __shfl_xor(zsq, off, 64);     \
        if (lane == 0) OUT = zsq;                                               \
    }

// Fused P4 for point T of sub-tile S: gather chunk g of winning row from
// embf8 (L2-resident), dequant, store coalesced (lanes share t-order).
#define P4_ROW(S, T, GB, GS, NJJ)                                               \
    {                                                                           \
        int code = pidx[(S) & 1][(T)];                                          \
        const char* rb = (const char*)embf8 + (size_t)(code >> 4) * 4096        \
                       + (code & 15) * 16;                                      \
        float* obS = ob + (S) * SUBP + (T);                                     \
        _Pragma("unroll")                                                       \
        for (int jj = 0; jj < (NJJ); ++jj) {                                    \
            int g = (GB) + (GS) * jj;                                           \
            uint4 v = *(const uint4*)(rb + (g >> 2) * 1024 + (g & 3) * 256);    \
            uint32_t wd[4] = {v.x, v.y, v.z, v.w};                              \
            _Pragma("unroll")                                                   \
            for (int u = 0; u < 4; ++u) {                                       \
                int kk = (g >> 2) * 2 + (u >> 1);                               \
                int d0 = kk * 32 + (g & 3) * 8 + (u & 1) * 4;                   \
                floatx2 lo = __builtin_amdgcn_cvt_pk_f32_fp8((int)wd[u], false); \
                floatx2 hi = __builtin_amdgcn_cvt_pk_f32_fp8((int)wd[u], true); \
                obS[(d0 + 0) * T_] = lo[0] * (1.f / 1024.f);                    \
                obS[(d0 + 1) * T_] = lo[1] * (1.f / 1024.f);                    \
                obS[(d0 + 2) * T_] = hi[0] * (1.f / 1024.f);                    \
                obS[(d0 + 3) * T_] = hi[1] * (1.f / 1024.f);                    \
            }                                                                   \
        }                                                                       \
    }

#define VQ_PREFETCH(QQ, EH, J)                                                  \
    {                                                                           \
        const char* p_ = ebL + (size_t)(J) * 4096;                              \
        _Pragma("unroll")                                                       \
        for (int i = 0; i < 4; ++i)                                             \
            QQ[i] = *(const longx2*)(p_ + i * 1024);                            \
        EH = esqh[(ct0 + (J)) * 16 + ml];                                       \
    }

// R3's verified STEP: 32 MFMA (4 point-sets x 8 k-frags), eh-subtract.
#define VQ_STEP(QQ, EH, J)                                                      \
    {                                                                           \
        floatx4 a0 = {0.f,0.f,0.f,0.f}, a1 = {0.f,0.f,0.f,0.f};                 \
        floatx4 a2 = {0.f,0.f,0.f,0.f}, a3 = {0.f,0.f,0.f,0.f};                 \
        _Pragma("unroll")                                                       \
        for (int i = 0; i < 4; ++i) {                                           \
            long bf0 = QQ[i][0], bf1 = QQ[i][1];                                \
            a0 = __builtin_amdgcn_mfma_f32_16x16x32_fp8_fp8(afr[0][2*i],   bf0, a0, 0, 0, 0); \
            a1 = __builtin_amdgcn_mfma_f32_16x16x32_fp8_fp8(afr[1][2*i],   bf0, a1, 0, 0, 0); \
            a2 = __builtin_amdgcn_mfma_f32_16x16x32_fp8_fp8(afr[2][2*i],   bf0, a2, 0, 0, 0); \
            a3 = __builtin_amdgcn_mfma_f32_16x16x32_fp8_fp8(afr[3][2*i],   bf0, a3, 0, 0, 0); \
            a0 = __builtin_amdgcn_mfma_f32_16x16x32_fp8_fp8(afr[0][2*i+1], bf1, a0, 0, 0, 0); \
            a1 = __builtin_amdgcn_mfma_f32_16x16x32_fp8_fp8(afr[1][2*i+1], bf1, a1, 0, 0, 0); \
            a2 = __builtin_amdgcn_mfma_f32_16x16x32_fp8_fp8(afr[2][2*i+1], bf1, a2, 0, 0, 0); \
            a3 = __builtin_amdgcn_mfma_f32_16x16x32_fp8_fp8(afr[3][2*i+1], bf1, a3, 0, 0, 0); \
        }                                                                       \
        unsigned cbits = (unsigned)((ct0 + (J)) * 16 + ml);                     \
        _Pragma("unroll")                                                       \
        for (int i = 0; i < 4; ++i) {                                           \
            float d0 = (EH) - a0[i];                                            \
            bv[0][i] = fminf(bv[0][i], __uint_as_float((__float_as_uint(d0) & hi_mask) | cbits)); \
            float d1 = (EH) - a1[i];                                            \
            bv[1][i] = fminf(bv[1][i], __uint_as_float((__float_as_uint(d1) & hi_mask) | cbits)); \
            float d2 = (EH) - a2[i];                                            \
            bv[2][i] = fminf(bv[2][i], __uint_as_float((__float_as_uint(d2) & hi_mask) | cbits)); \
            float d3 = (EH) - a3[i];                                            \
            bv[3][i] = fminf(bv[3][i], __uint_as_float((__float_as_uint(d3) & hi_mask) | cbits)); \
        }                                                                       \
    }

    // ---- prologue: all 8 waves stage sub-tile 0 ----
    P1_BODY(0, w, 8, zred0[w])
    __syncthreads();

    #pragma unroll 1
    for (int it = 0; it < NSUB; ++it) {
        if (w < 4) {
            // ================= compute waves: k-loop on xs[it&1] =========
            const unsigned char* xsc = xs[it & 1];
            int ct0 = w * 16;
            const char* ebL = (const char*)embf8 + (size_t)ct0 * 4096
                            + (size_t)lane * 16;
            longx2 qqA[4], qqB[4];
            float ehA, ehB;
            VQ_PREFETCH(qqA, ehA, 0)
            long afr[4][8];
            #pragma unroll
            for (int s = 0; s < 4; ++s) {
                int pnt = s * 16 + ml;
                #pragma unroll
                for (int kk = 0; kk < 8; ++kk) {
                    int c = 2 * kk + (quad >> 1), h = quad & 1;
                    afr[s][kk] = *(const long*)&xsc[pnt * 256 + ((c ^ ml) << 4)
                                                    + ((h ^ (s & 1)) << 3)];
                }
            }
            float bv[4][4];
            #pragma unroll
            for (int s = 0; s < 4; ++s)
                #pragma unroll
                for (int i = 0; i < 4; ++i) bv[s][i] = 1e30f;
            const unsigned hi_mask = 0xFFFFFC00u;

            #pragma unroll 1
            for (int j = 0; j < 16; j += 2) {
                VQ_PREFETCH(qqB, ehB, j + 1)
                VQ_STEP(qqA, ehA, j)
                if (j + 2 < 16) VQ_PREFETCH(qqA, ehA, j + 2)
                VQ_STEP(qqB, ehB, j + 1)
            }

            // publish packed candidates
            #pragma unroll
            for (int s = 0; s < 4; ++s)
                #pragma unroll
                for (int i = 0; i < 4; ++i) {
                    float v = bv[s][i];
                    #pragma unroll
                    for (int off = 1; off < 16; off <<= 1)
                        v = fminf(v, __shfl_xor(v, off, 64));
                    if (ml == 0) wvals[w][s * 16 + quad * 4 + i] = v;
                }
        } else if (w < 6) {
            // ================= P1 waves: stage sub-tile it+1 =============
            if (it + 1 < NSUB)
                P1_BODY(it + 1, (w & 1), 2, zredp[(it + 1) & 1][w & 1])
        } else {
            // ================= P4 waves: drain sub-tile it-1 =============
            if (it >= 1) {
                int local = tid & 127;
                int t = local & 63, gb = local >> 6;
                P4_ROW(it - 1, t, gb, 2, 8)
            }
        }
        __syncthreads();                       // barrier A

        // ---- merge (64 lanes of wave 0) ----
        if (tid < 64) {
            int t = tid;
            float wv = fminf(fminf(wvals[0][t], wvals[1][t]),
                             fminf(wvals[2][t], wvals[3][t]));
            pidx[it & 1][t] = (int)(__float_as_uint(wv) & 1023u);
            float lsum = wv;
            #pragma unroll
            for (int off = 32; off; off >>= 1) lsum += __shfl_xor(lsum, off, 64);
            if (t == 0) {
                float zs;
                if (it == 0)
                    zs = zred0[0] + zred0[1] + zred0[2] + zred0[3]
                       + zred0[4] + zred0[5] + zred0[6] + zred0[7];
                else
                    zs = zredp[it & 1][0] + zredp[it & 1][1];
                atomicAdd(lossp, (zs + lsum * (2.0f / 1024.f))
                                 * (1.25f / 16777216.0f));   // 1.25/(N*D)
            }
        }
        __syncthreads();                       // barrier B
    }

    // ---- epilogue: all 8 waves drain the last sub-tile ----
    {
        int t = tid & 63, gb = tid >> 6;
        P4_ROW(NSUB - 1, t, gb, 8, 2)
    }

#undef P1_BODY
#undef P4_ROW
#undef VQ_PREFETCH
#undef VQ_STEP
}

extern "C" void kernel_launch(void* const* d_in, const int* in_sizes, int n_in,
                              void* d_out, int out_size, void* d_ws, size_t ws_size,
                              hipStream_t stream) {
    (void)in_sizes; (void)n_in; (void)out_size; (void)ws_size;
    const float* z   = (const float*)d_in[0];
    const float* emb = (const float*)d_in[1];

    uint32_t* embf8 = (uint32_t*)d_ws;                              // 256 KiB
    float*    esqh  = (float*)((char*)d_ws + (size_t)K_ * D_);      // 4 KiB

    float* out0  = (float*)d_out;
    float* lossp = out0 + (size_t)N_ * D_;

    emb_prep<<<K_ / 4, 256, 0, stream>>>(emb, embf8, esqh, lossp);
    vq_main<<<N_ / (NSUB * SUBP), 512, 0, stream>>>(z, embf8, esqh, out0, lossp);
}